// Round 17
// baseline (86.755 us; speedup 1.0000x reference)
//
#include <hip/hip_runtime.h>
#include <hip/hip_bf16.h>
#include <cstdint>
#include <cstddef>

#define S_LEN 2048
#define DM 512
#define DK 64

typedef __attribute__((ext_vector_type(4))) float f32x4;
typedef __attribute__((ext_vector_type(8))) short short8;
typedef __attribute__((ext_vector_type(8))) _Float16 f16x8;

__device__ __forceinline__ unsigned short f2bf(float f) {
  union { float f; uint32_t u; } c; c.f = f;
  uint32_t u = c.u;
  u += 0x7FFF + ((u >> 16) & 1);   // round-to-nearest-even
  return (unsigned short)(u >> 16);
}

__device__ __forceinline__ unsigned short f2h(float f) {
  union { _Float16 h; unsigned short u; } c; c.h = (_Float16)f; return c.u;
}

__device__ __forceinline__ unsigned int pkbf(float a, float b) {
  union { __hip_bfloat162 h; unsigned int u; } c;
  c.h = __float22bfloat162_rn(make_float2(a, b));
  return c.u;
}

__device__ __forceinline__ unsigned int pkh(float a, float b) {
  auto pk = __builtin_amdgcn_cvt_pkrtz(a, b);   // __fp16 ext_vector(2)
  union { decltype(pk) h; unsigned int u; } c;
  c.h = pk;
  return c.u;
}

// load 8 fp32, scale, round to bf16x8 (packed)
__device__ __forceinline__ short8 ldq8(const float* p, float s) {
  float4 a = *reinterpret_cast<const float4*>(p);
  float4 b = *reinterpret_cast<const float4*>(p + 4);
  union { short8 v; unsigned int u[4]; } r;
  r.u[0] = pkbf(a.x * s, a.y * s);
  r.u[1] = pkbf(a.z * s, a.w * s);
  r.u[2] = pkbf(b.x * s, b.y * s);
  r.u[3] = pkbf(b.z * s, b.w * s);
  return r.v;
}

// async global -> LDS, 16B per lane, LDS dest = wave-uniform base + lane*16
__device__ __forceinline__ void gl2lds16(const unsigned short* g, unsigned short* l) {
  __builtin_amdgcn_global_load_lds(
      (const __attribute__((address_space(1))) unsigned int*)g,
      (__attribute__((address_space(3))) unsigned int*)l, 16, 0, 0);
}

// exchange: a.lanes[32:63] <-> b.lanes[0:31]
#define SWAP32(a, b) asm volatile("v_permlane32_swap_b32 %0, %1" : "+v"(a), "+v"(b))
// exchange within 32-lane halves: a.lanes[16:31]<->b.lanes[0:15], a[48:63]<->b[32:47]
#define SWAP16(a, b) asm volatile("v_permlane16_swap_b32 %0, %1" : "+v"(a), "+v"(b))

// ---------------- fused prep: K->bf16, W->bf16, V->f16 transposed ----------------
__global__ __launch_bounds__(256) void prep_kernel(const float* __restrict__ K,
                                                   const float* __restrict__ V,
                                                   const float* __restrict__ W,
                                                   unsigned short* __restrict__ Kb,
                                                   unsigned short* __restrict__ Vt,
                                                   unsigned short* __restrict__ Wb) {
  __shared__ unsigned short tile[64][66];
  const int bid = blockIdx.x;
  const int t = threadIdx.x;
  if (bid < 4096) {                      // K convert -> bf16
    int i = (bid * 256 + t) * 4;
    float4 v = *reinterpret_cast<const float4*>(K + i);
    ushort4 o;
    o.x = f2bf(v.x); o.y = f2bf(v.y); o.z = f2bf(v.z); o.w = f2bf(v.w);
    *reinterpret_cast<ushort4*>(Kb + i) = o;
  } else if (bid < 4352) {               // W convert -> bf16
    int i = ((bid - 4096) * 256 + t) * 4;
    float4 v = *reinterpret_cast<const float4*>(W + i);
    ushort4 o;
    o.x = f2bf(v.x); o.y = f2bf(v.y); o.z = f2bf(v.z); o.w = f2bf(v.w);
    *reinterpret_cast<ushort4*>(Wb + i) = o;
  } else {                               // V transpose -> f16: Vt[nh][d][l]
    const int r = bid - 4352;            // 1024 blocks
    const int lt = r & 31;
    const int nh = r >> 5;
    const int n = nh >> 3, h = nh & 7;
    #pragma unroll
    for (int it = 0; it < 16; ++it) {
      int e = it * 256 + t;
      int l = e >> 6, d = e & 63;
      float v = V[((size_t)(n * S_LEN + lt * 64 + l)) * DM + h * DK + d];
      tile[l][d] = f2h(v);
    }
    __syncthreads();
    #pragma unroll
    for (int it = 0; it < 16; ++it) {
      int e = it * 256 + t;
      int d = e >> 6, l = e & 63;
      Vt[((size_t)(nh * DK + d)) * S_LEN + lt * 64 + l] = tile[l][d];
    }
  }
}

// ---------------- flash attention: qt=4 (64 q/wave), key-split, in-register P ----------------
// r13's proven layout/sync/arithmetic with 4 Q-fragments per wave: the same 8 ds_read_b128
// per 32-key group now feed 32 MFMAs (was 16) -- LDS read traffic per MFMA halves, the
// largest cycle term at r16. 4 waves = 2qw x 2kw, block=128q, KBLK=64, grid (16,32).
// K and V share SH[4] so the 32KB epilogue scratch is contiguous.
__global__ __launch_bounds__(256, 3) void attn_kernel(const float* __restrict__ Qf,
                                                      const unsigned short* __restrict__ Kb,
                                                      const unsigned short* __restrict__ Vt,
                                                      unsigned short* __restrict__ Ab) {
  __shared__ __align__(16) unsigned short SH[4][64 * 64];  // [0..1]=K bufs, [2..3]=V bufs
  __shared__ float lsL[2][4][16];                          // [qw][qt][c] kw=1 partials

  // T1: bijective remap so XCD x handles nh in [4x, 4x+4)
  const int dlin = blockIdx.x + 16 * blockIdx.y;   // grid (16,32), 512 blocks
  const int xcd = dlin & 7;
  const int mm = dlin >> 3;                        // 0..63
  const int nh = xcd * 4 + (mm & 3);
  const int qtb = mm >> 2;                         // 0..15
  const int n = nh >> 3, h = nh & 7;
  const int wave = threadIdx.x >> 6;               // 0..3
  const int lane = threadIdx.x & 63;
  const int c = lane & 15;          // MFMA row/col index
  const int g = lane >> 4;          // lane group 0..3
  const int qw = wave >> 1;         // q-half 0..1
  const int kw = wave & 1;          // key-half this wave consumes
  const int c7 = c & 7;

  const int qbase = qtb * 128 + qw * 64;
  const float C2 = 0.063758716f;    // log2(e)/sqrt(512), folded into Q

  // Q B-fragments (16x16x32): lane (c,g) holds Q[qbase+qt*16+c][dkc*32+g*8+e]
  short8 qfrag[4][2];
  #pragma unroll
  for (int qt = 0; qt < 4; ++qt)
    #pragma unroll
    for (int dkc = 0; dkc < 2; ++dkc)
      qfrag[qt][dkc] = ldq8(
          Qf + ((size_t)(n * S_LEN + qbase + qt * 16 + c)) * DM + h * DK + dkc * 32 + g * 8, C2);

  f32x4 oacc[4][4];
  #pragma unroll
  for (int qt = 0; qt < 4; ++qt)
    #pragma unroll
    for (int dt = 0; dt < 4; ++dt) oacc[qt][dt] = (f32x4){0.f, 0.f, 0.f, 0.f};
  float lsum[4] = {0.f, 0.f, 0.f, 0.f};

  // Staging (r13 pattern): wave w stages 16 K rows + 16 V rows (2+2 gl_lds).
  const int srow = lane >> 3;
  const int csrc = (lane & 7) ^ srow;   // pre-swizzled source chunk (rule #21)
  const unsigned short* ksrc = Kb + ((size_t)(n * S_LEN + srow)) * DM + h * DK + csrc * 8;
  const unsigned short* vsrc = Vt + ((size_t)(nh * DK + srow)) * S_LEN + csrc * 8;
  const int kr0 = wave * 16;

#define STAGE(B_, L0_) do {                                                        \
    _Pragma("unroll")                                                              \
    for (int u = 0; u < 2; ++u)                                                    \
      gl2lds16(ksrc + (size_t)((L0_) + kr0 + u * 8) * DM, &SH[B_][(kr0 + u * 8) * 64]); \
    _Pragma("unroll")                                                              \
    for (int u = 0; u < 2; ++u)                                                    \
      gl2lds16(vsrc + (size_t)(kr0 + u * 8) * S_LEN + (L0_), &SH[2 + (B_)][(kr0 + u * 8) * 64]); \
  } while (0)

#define COMPUTE(B_) do {                                                           \
    short8 kf[2][2];                                                               \
    _Pragma("unroll")                                                              \
    for (int ks = 0; ks < 2; ++ks)                                                 \
      _Pragma("unroll")                                                            \
      for (int dkc = 0; dkc < 2; ++dkc)                                            \
        kf[ks][dkc] = *reinterpret_cast<const short8*>(                            \
            &SH[B_][(kw * 32 + ks * 16 + c) * 64 + (((dkc * 4 + g) ^ c7) << 3)]);  \
    f16x8 vfv[4];                                                                  \
    _Pragma("unroll")                                                              \
    for (int dt = 0; dt < 4; ++dt)                                                 \
      vfv[dt] = *reinterpret_cast<const f16x8*>(                                   \
          &SH[2 + (B_)][(dt * 16 + c) * 64 + (((kw * 4 + g) ^ c7) << 3)]);         \
    _Pragma("unroll")                                                              \
    for (int qt = 0; qt < 4; ++qt) {                                               \
      f32x4 s0 = (f32x4){0.f, 0.f, 0.f, 0.f};                                      \
      f32x4 s1 = (f32x4){0.f, 0.f, 0.f, 0.f};                                      \
      s0 = __builtin_amdgcn_mfma_f32_16x16x32_bf16(kf[0][0], qfrag[qt][0], s0, 0, 0, 0); \
      s1 = __builtin_amdgcn_mfma_f32_16x16x32_bf16(kf[1][0], qfrag[qt][0], s1, 0, 0, 0); \
      s0 = __builtin_amdgcn_mfma_f32_16x16x32_bf16(kf[0][1], qfrag[qt][1], s0, 0, 0, 0); \
      s1 = __builtin_amdgcn_mfma_f32_16x16x32_bf16(kf[1][1], qfrag[qt][1], s1, 0, 0, 0); \
      float pa0 = __builtin_amdgcn_exp2f(s0[0]);                                   \
      float pa1 = __builtin_amdgcn_exp2f(s0[1]);                                   \
      float pa2 = __builtin_amdgcn_exp2f(s0[2]);                                   \
      float pa3 = __builtin_amdgcn_exp2f(s0[3]);                                   \
      float pb0 = __builtin_amdgcn_exp2f(s1[0]);                                   \
      float pb1 = __builtin_amdgcn_exp2f(s1[1]);                                   \
      float pb2 = __builtin_amdgcn_exp2f(s1[2]);                                   \
      float pb3 = __builtin_amdgcn_exp2f(s1[3]);                                   \
      lsum[qt] += ((pa0 + pa1) + (pa2 + pa3)) + ((pb0 + pb1) + (pb2 + pb3));       \
      unsigned int pA = pkh(pa0, pa1);                                             \
      unsigned int pB = pkh(pa2, pa3);                                             \
      unsigned int pC = pkh(pb0, pb1);                                             \
      unsigned int pD = pkh(pb2, pb3);                                             \
      SWAP32(pA, pC); SWAP32(pB, pD);                                              \
      SWAP16(pA, pC); SWAP16(pB, pD);                                              \
      union { f16x8 v; unsigned int u[4]; } pf;                                    \
      pf.u[0] = pA; pf.u[1] = pB; pf.u[2] = pC; pf.u[3] = pD;                      \
      _Pragma("unroll")                                                            \
      for (int dt = 0; dt < 4; ++dt)                                               \
        oacc[qt][dt] = __builtin_amdgcn_mfma_f32_16x16x32_f16(                     \
            vfv[dt], pf.v, oacc[qt][dt], 0, 0, 0);                                 \
    }                                                                              \
  } while (0)

  STAGE(0, 0);
  asm volatile("s_waitcnt vmcnt(0)" ::: "memory");
  __syncthreads();

  for (int l0 = 0; l0 < S_LEN; l0 += 64) {
    const int cur = (l0 >> 6) & 1;
    if (l0 + 64 < S_LEN) STAGE(cur ^ 1, l0 + 64);
    COMPUTE(cur);
    __syncthreads();   // drains vmcnt + fences buffer reuse -- proven r4-r16
  }
#undef STAGE
#undef COMPUTE

  // per-wave denom (32 keys) per q: reduce over g
  #pragma unroll
  for (int qt = 0; qt < 4; ++qt) {
    lsum[qt] += __shfl_xor(lsum[qt], 16);
    lsum[qt] += __shfl_xor(lsum[qt], 32);
  }

  // ---- cross-kw reduction: kw=1 dumps O partials + lsum; kw=0 adds and writes ----
  float* red = reinterpret_cast<float*>(&SH[0][0]);   // 32KB contiguous scratch
  if (kw == 1) {
    #pragma unroll
    for (int qt = 0; qt < 4; ++qt)
      #pragma unroll
      for (int dt = 0; dt < 4; ++dt)
        *reinterpret_cast<f32x4*>(red + (((qw * 4 + qt) * 4 + dt) << 8) + lane * 4) = oacc[qt][dt];
    if (lane < 16) {
      #pragma unroll
      for (int qt = 0; qt < 4; ++qt) lsL[qw][qt][lane] = lsum[qt];
    }
  }
  __syncthreads();
  if (kw == 0) {
    #pragma unroll
    for (int qt = 0; qt < 4; ++qt) {
      #pragma unroll
      for (int dt = 0; dt < 4; ++dt)
        oacc[qt][dt] += *reinterpret_cast<const f32x4*>(
            red + (((qw * 4 + qt) * 4 + dt) << 8) + lane * 4);
      const float rl = 1.f / (lsum[qt] + lsL[qw][qt][c]);
      unsigned short* ab = Ab + ((size_t)(n * S_LEN + qbase + qt * 16 + c)) * DM + h * DK;
      #pragma unroll
      for (int dt = 0; dt < 4; ++dt) {
        uint2 w;
        w.x = pkbf(oacc[qt][dt][0] * rl, oacc[qt][dt][1] * rl);
        w.y = pkbf(oacc[qt][dt][2] * rl, oacc[qt][dt][3] * rl);
        *reinterpret_cast<uint2*>(ab + dt * 16 + g * 4) = w;
      }
    }
  }
}

// ---------------- bf16 MFMA output projection: out = A @ W^T + b ----------------
__global__ __launch_bounds__(256, 2) void proj_kernel(const unsigned short* __restrict__ Ab,
                                                      const unsigned short* __restrict__ Wb,
                                                      const float* __restrict__ bias,
                                                      float* __restrict__ out) {
  __shared__ __align__(16) unsigned short At[2][128 * 64];  // [m][k], 128B rows
  __shared__ __align__(16) unsigned short Wt[2][64 * 64];   // [o][k], 128B rows

  const int m0 = blockIdx.x * 128;
  const int o0 = blockIdx.y * 64;
  const int wave = threadIdx.x >> 6;
  const int lane = threadIdx.x & 63;
  const int lr = lane & 15;
  const int lg = lane >> 4;
  const int r7 = lr & 7;
  const int wm = (wave >> 1) * 64;
  const int wn = (wave & 1) * 32;

  const int srow = lane >> 3;
  const int csrc = (lane & 7) ^ srow;
  const unsigned short* asrc = Ab + ((size_t)(m0 + wave * 32 + srow)) * DM + csrc * 8;
  const unsigned short* wsrc = Wb + ((size_t)(o0 + wave * 16 + srow)) * DM + csrc * 8;

  float bv[2];
  #pragma unroll
  for (int nf = 0; nf < 2; ++nf) bv[nf] = bias[o0 + wn + nf * 16 + lr];

  f32x4 acc[4][2];
  #pragma unroll
  for (int mf = 0; mf < 4; ++mf)
    #pragma unroll
    for (int nf = 0; nf < 2; ++nf) acc[mf][nf] = (f32x4){0.f, 0.f, 0.f, 0.f};

#define PSTAGE(B_, KB_) do {                                                       \
    _Pragma("unroll")                                                              \
    for (int u = 0; u < 4; ++u)                                                    \
      gl2lds16(asrc + (size_t)(u * 8) * DM + (KB_), &At[B_][(wave * 32 + u * 8) * 64]); \
    _Pragma("unroll")                                                              \
    for (int u = 0; u < 2; ++u)                                                    \
      gl2lds16(wsrc + (size_t)(u * 8) * DM + (KB_), &Wt[B_][(wave * 16 + u * 8) * 64]); \
  } while (0)

#define PCOMPUTE(B_) do {                                                          \
    _Pragma("unroll")                                                              \
    for (int kc = 0; kc < 2; ++kc) {                                               \
      const int sw = ((kc * 4 + lg) ^ r7) << 3;                                    \
      short8 af[4], wf[2];                                                         \
      _Pragma("unroll")                                                            \
      for (int mf = 0; mf < 4; ++mf)                                               \
        af[mf] = *reinterpret_cast<const short8*>(&At[B_][(wm + mf * 16 + lr) * 64 + sw]); \
      _Pragma("unroll")                                                            \
      for (int nf = 0; nf < 2; ++nf)                                               \
        wf[nf] = *reinterpret_cast<const short8*>(&Wt[B_][(wn + nf * 16 + lr) * 64 + sw]); \
      _Pragma("unroll")                                                            \
      for (int mf = 0; mf < 4; ++mf)                                               \
        _Pragma("unroll")                                                          \
        for (int nf = 0; nf < 2; ++nf)                                             \
          acc[mf][nf] = __builtin_amdgcn_mfma_f32_16x16x32_bf16(af[mf], wf[nf], acc[mf][nf], 0, 0, 0); \
    }                                                                              \
  } while (0)

  PSTAGE(0, 0);
  asm volatile("s_waitcnt vmcnt(0)" ::: "memory");
  __syncthreads();

  for (int kb = 0; kb < DM; kb += 64) {
    const int cur = (kb >> 6) & 1;
    if (kb + 64 < DM) PSTAGE(cur ^ 1, kb + 64);
    PCOMPUTE(cur);
    __syncthreads();
  }
#undef PSTAGE
#undef PCOMPUTE

  #pragma unroll
  for (int mf = 0; mf < 4; ++mf) {
    #pragma unroll
    for (int j = 0; j < 4; ++j) {
      float* op = out + (size_t)(m0 + wm + mf * 16 + lg * 4 + j) * DM + o0 + wn + lr;
      #pragma unroll
      for (int nf = 0; nf < 2; ++nf)
        op[nf * 16] = acc[mf][nf][j] + bv[nf];
    }
  }
}

extern "C" void kernel_launch(void* const* d_in, const int* in_sizes, int n_in,
                              void* d_out, int out_size, void* d_ws, size_t ws_size,
                              hipStream_t stream) {
  const float* Q = (const float*)d_in[0];
  const float* K = (const float*)d_in[1];
  const float* V = (const float*)d_in[2];
  const float* W = (const float*)d_in[3];
  const float* b = (const float*)d_in[4];
  float* out = (float*)d_out;

  // ws layout: Kb(8MB) | Vt(8MB) | Ab bf16(8MB) | Wb bf16(0.5MB)
  char* ws = (char*)d_ws;
  unsigned short* Kb = (unsigned short*)(ws);
  unsigned short* Vt = (unsigned short*)(ws + 8388608);
  unsigned short* Ab = (unsigned short*)(ws + 16777216);
  unsigned short* Wb = (unsigned short*)(ws + 25165824);

  prep_kernel<<<5376, 256, 0, stream>>>(K, V, W, Kb, Vt, Wb);
  attn_kernel<<<dim3(16, 32), 256, 0, stream>>>(Q, Kb, Vt, Ab);
  proj_kernel<<<dim3(64, 8), 256, 0, stream>>>(Ab, Wb, b, out);
}

// Round 18
// 68.950 us; speedup vs baseline: 1.2582x; 1.2582x over previous
//
#include <hip/hip_runtime.h>
#include <hip/hip_bf16.h>
#include <cstdint>
#include <cstddef>

#define S_LEN 2048
#define DM 512
#define DK 64

typedef __attribute__((ext_vector_type(4))) float f32x4;
typedef __attribute__((ext_vector_type(8))) short short8;
typedef __attribute__((ext_vector_type(8))) _Float16 f16x8;

__device__ __forceinline__ unsigned short f2bf(float f) {
  union { float f; uint32_t u; } c; c.f = f;
  uint32_t u = c.u;
  u += 0x7FFF + ((u >> 16) & 1);   // round-to-nearest-even
  return (unsigned short)(u >> 16);
}

__device__ __forceinline__ unsigned short f2h(float f) {
  union { _Float16 h; unsigned short u; } c; c.h = (_Float16)f; return c.u;
}

__device__ __forceinline__ unsigned int pkbf(float a, float b) {
  union { __hip_bfloat162 h; unsigned int u; } c;
  c.h = __float22bfloat162_rn(make_float2(a, b));
  return c.u;
}

__device__ __forceinline__ unsigned int pkh(float a, float b) {
  auto pk = __builtin_amdgcn_cvt_pkrtz(a, b);   // __fp16 ext_vector(2)
  union { decltype(pk) h; unsigned int u; } c;
  c.h = pk;
  return c.u;
}

// load 8 fp32, scale, round to bf16x8 (packed)
__device__ __forceinline__ short8 ldq8(const float* p, float s) {
  float4 a = *reinterpret_cast<const float4*>(p);
  float4 b = *reinterpret_cast<const float4*>(p + 4);
  union { short8 v; unsigned int u[4]; } r;
  r.u[0] = pkbf(a.x * s, a.y * s);
  r.u[1] = pkbf(a.z * s, a.w * s);
  r.u[2] = pkbf(b.x * s, b.y * s);
  r.u[3] = pkbf(b.z * s, b.w * s);
  return r.v;
}

// async global -> LDS, 16B per lane, LDS dest = wave-uniform base + lane*16
__device__ __forceinline__ void gl2lds16(const unsigned short* g, unsigned short* l) {
  __builtin_amdgcn_global_load_lds(
      (const __attribute__((address_space(1))) unsigned int*)g,
      (__attribute__((address_space(3))) unsigned int*)l, 16, 0, 0);
}

// exchange: a.lanes[32:63] <-> b.lanes[0:31]
#define SWAP32(a, b) asm volatile("v_permlane32_swap_b32 %0, %1" : "+v"(a), "+v"(b))
// exchange within 32-lane halves: a.lanes[16:31]<->b.lanes[0:15], a[48:63]<->b[32:47]
#define SWAP16(a, b) asm volatile("v_permlane16_swap_b32 %0, %1" : "+v"(a), "+v"(b))

// ---------------- fused prep: K->bf16, W->bf16, V->f16 transposed ----------------
__global__ __launch_bounds__(256) void prep_kernel(const float* __restrict__ K,
                                                   const float* __restrict__ V,
                                                   const float* __restrict__ W,
                                                   unsigned short* __restrict__ Kb,
                                                   unsigned short* __restrict__ Vt,
                                                   unsigned short* __restrict__ Wb) {
  __shared__ unsigned short tile[64][66];
  const int bid = blockIdx.x;
  const int t = threadIdx.x;
  if (bid < 4096) {                      // K convert -> bf16
    int i = (bid * 256 + t) * 4;
    float4 v = *reinterpret_cast<const float4*>(K + i);
    ushort4 o;
    o.x = f2bf(v.x); o.y = f2bf(v.y); o.z = f2bf(v.z); o.w = f2bf(v.w);
    *reinterpret_cast<ushort4*>(Kb + i) = o;
  } else if (bid < 4352) {               // W convert -> bf16
    int i = ((bid - 4096) * 256 + t) * 4;
    float4 v = *reinterpret_cast<const float4*>(W + i);
    ushort4 o;
    o.x = f2bf(v.x); o.y = f2bf(v.y); o.z = f2bf(v.z); o.w = f2bf(v.w);
    *reinterpret_cast<ushort4*>(Wb + i) = o;
  } else {                               // V transpose -> f16: Vt[nh][d][l]
    const int r = bid - 4352;            // 1024 blocks
    const int lt = r & 31;
    const int nh = r >> 5;
    const int n = nh >> 3, h = nh & 7;
    #pragma unroll
    for (int it = 0; it < 16; ++it) {
      int e = it * 256 + t;
      int l = e >> 6, d = e & 63;
      float v = V[((size_t)(n * S_LEN + lt * 64 + l)) * DM + h * DK + d];
      tile[l][d] = f2h(v);
    }
    __syncthreads();
    #pragma unroll
    for (int it = 0; it < 16; ++it) {
      int e = it * 256 + t;
      int d = e >> 6, l = e & 63;
      Vt[((size_t)(nh * DK + d)) * S_LEN + lt * 64 + l] = tile[l][d];
    }
  }
}

// ---------------- flash attention: r16 geometry + counted-vmcnt (T4, race-fixed) ----------------
// r16: KBLK=128, 8 waves (4qw x 2kw), 512-thread blocks, 16 waves/CU, in-register P.
// NEW: per-period drain replaced by counted s_waitcnt vmcnt(4) + asm s_barrier WITH
// "memory" clobber (compiler fence). r8's race was ds_reads hoisted above the bare
// s_barrier builtin (no fence, rule #18 cousin) -- reading rows another wave's DMA
// hadn't landed. The fenced barrier closes that; next tile's 4 loads stay in flight.
__global__ __launch_bounds__(512, 4) void attn_kernel(const float* __restrict__ Qf,
                                                      const unsigned short* __restrict__ Kb,
                                                      const unsigned short* __restrict__ Vt,
                                                      unsigned short* __restrict__ Ab) {
  __shared__ __align__(16) unsigned short KT[2][2][64 * 64];  // [buf][sub][key][d] bf16
  __shared__ __align__(16) unsigned short VT[2][2][64 * 64];  // [buf][sub][d][key] f16
  __shared__ float lsL[4][2][16];                             // [qw][qt][c] kw=1 partials

  // T1: bijective remap so XCD x handles nh in [4x, 4x+4)
  const int dlin = blockIdx.x + 16 * blockIdx.y;   // grid (16,32), 512 blocks
  const int xcd = dlin & 7;
  const int mm = dlin >> 3;                        // 0..63
  const int nh = xcd * 4 + (mm & 3);
  const int qtb = mm >> 2;                         // 0..15
  const int n = nh >> 3, h = nh & 7;
  const int wave = threadIdx.x >> 6;               // 0..7
  const int lane = threadIdx.x & 63;
  const int c = lane & 15;          // MFMA row/col index
  const int g = lane >> 4;          // lane group 0..3
  const int qw = wave >> 1;         // q-quarter 0..3
  const int kw = wave & 1;          // key-subtile this wave consumes
  const int c7 = c & 7;

  const int qbase = qtb * 128 + qw * 32;
  const float C2 = 0.063758716f;    // log2(e)/sqrt(512), folded into Q

  // Q B-fragments (16x16x32): lane (c,g) holds Q[qbase+qt*16+c][dkc*32+g*8+e]
  short8 qfrag[2][2];
  #pragma unroll
  for (int qt = 0; qt < 2; ++qt)
    #pragma unroll
    for (int dkc = 0; dkc < 2; ++dkc)
      qfrag[qt][dkc] = ldq8(
          Qf + ((size_t)(n * S_LEN + qbase + qt * 16 + c)) * DM + h * DK + dkc * 32 + g * 8, C2);

  f32x4 oacc[2][4];
  #pragma unroll
  for (int qt = 0; qt < 2; ++qt)
    #pragma unroll
    for (int dt = 0; dt < 4; ++dt) oacc[qt][dt] = (f32x4){0.f, 0.f, 0.f, 0.f};
  float lsum[2] = {0.f, 0.f};

  // Staging: waves 0-3 stage K (sub=(w>>1)&1, half=w&1 -> 32 rows), waves 4-7 stage V.
  // 4 gl_lds units of 8 rows x 128B each. Pre-swizzled source chunk (rule #21).
  const int srow = lane >> 3;
  const int csrc = (lane & 7) ^ srow;
  const bool isK = (wave < 4);
  const int sub = (wave >> 1) & 1;
  const int half = wave & 1;
  const unsigned short* sbase = isK
      ? Kb + ((size_t)(n * S_LEN + sub * 64 + half * 32 + srow)) * DM + h * DK + csrc * 8
      : Vt + ((size_t)(nh * DK + half * 32 + srow)) * S_LEN + sub * 64 + csrc * 8;
  unsigned short* dbase[2] = {
      isK ? &KT[0][sub][(half * 32) * 64] : &VT[0][sub][(half * 32) * 64],
      isK ? &KT[1][sub][(half * 32) * 64] : &VT[1][sub][(half * 32) * 64] };

#define STAGE(B_, L0_) do {                                                        \
    if (isK) {                                                                     \
      _Pragma("unroll")                                                            \
      for (int u = 0; u < 4; ++u)                                                  \
        gl2lds16(sbase + (size_t)((L0_) + u * 8) * DM, dbase[B_] + (u * 8) * 64);  \
    } else {                                                                       \
      _Pragma("unroll")                                                            \
      for (int u = 0; u < 4; ++u)                                                  \
        gl2lds16(sbase + (size_t)(u * 8) * S_LEN + (L0_), dbase[B_] + (u * 8) * 64); \
    }                                                                              \
  } while (0)

  // one 32-key group (ks2) of this wave's sub-tile: r13/r15/r16's proven COMPUTE body
#define COMPUTE32(B_, KS2_) do {                                                   \
    short8 kf[2][2];                                                               \
    _Pragma("unroll")                                                              \
    for (int ks = 0; ks < 2; ++ks)                                                 \
      _Pragma("unroll")                                                            \
      for (int dkc = 0; dkc < 2; ++dkc)                                            \
        kf[ks][dkc] = *reinterpret_cast<const short8*>(                            \
            &KT[B_][kw][((KS2_) * 32 + ks * 16 + c) * 64 + (((dkc * 4 + g) ^ c7) << 3)]); \
    f32x4 s[2][2];                                                                 \
    _Pragma("unroll")                                                              \
    for (int qt = 0; qt < 2; ++qt)                                                 \
      _Pragma("unroll")                                                            \
      for (int ks = 0; ks < 2; ++ks) s[qt][ks] = (f32x4){0.f, 0.f, 0.f, 0.f};      \
    _Pragma("unroll")                                                              \
    for (int dkc = 0; dkc < 2; ++dkc)                                              \
      _Pragma("unroll")                                                            \
      for (int ks = 0; ks < 2; ++ks)                                               \
        _Pragma("unroll")                                                          \
        for (int qt = 0; qt < 2; ++qt)                                             \
          s[qt][ks] = __builtin_amdgcn_mfma_f32_16x16x32_bf16(                     \
              kf[ks][dkc], qfrag[qt][dkc], s[qt][ks], 0, 0, 0);                    \
    union { f16x8 v; unsigned int u[4]; } pf[2];                                   \
    _Pragma("unroll")                                                              \
    for (int qt = 0; qt < 2; ++qt) {                                               \
      float pa0 = __builtin_amdgcn_exp2f(s[qt][0][0]);                             \
      float pa1 = __builtin_amdgcn_exp2f(s[qt][0][1]);                             \
      float pa2 = __builtin_amdgcn_exp2f(s[qt][0][2]);                             \
      float pa3 = __builtin_amdgcn_exp2f(s[qt][0][3]);                             \
      float pb0 = __builtin_amdgcn_exp2f(s[qt][1][0]);                             \
      float pb1 = __builtin_amdgcn_exp2f(s[qt][1][1]);                             \
      float pb2 = __builtin_amdgcn_exp2f(s[qt][1][2]);                             \
      float pb3 = __builtin_amdgcn_exp2f(s[qt][1][3]);                             \
      lsum[qt] += ((pa0 + pa1) + (pa2 + pa3)) + ((pb0 + pb1) + (pb2 + pb3));       \
      unsigned int pA = pkh(pa0, pa1);                                             \
      unsigned int pB = pkh(pa2, pa3);                                             \
      unsigned int pC = pkh(pb0, pb1);                                             \
      unsigned int pD = pkh(pb2, pb3);                                             \
      SWAP32(pA, pC); SWAP32(pB, pD);                                              \
      SWAP16(pA, pC); SWAP16(pB, pD);                                              \
      pf[qt].u[0] = pA; pf[qt].u[1] = pB; pf[qt].u[2] = pC; pf[qt].u[3] = pD;      \
    }                                                                              \
    _Pragma("unroll")                                                              \
    for (int dt = 0; dt < 4; ++dt) {                                               \
      const f16x8 vf = *reinterpret_cast<const f16x8*>(                            \
          &VT[B_][kw][(dt * 16 + c) * 64 + ((((KS2_) * 4 + g) ^ c7) << 3)]);       \
      _Pragma("unroll")                                                            \
      for (int qt = 0; qt < 2; ++qt)                                               \
        oacc[qt][dt] = __builtin_amdgcn_mfma_f32_16x16x32_f16(                     \
            vf, pf[qt].v, oacc[qt][dt], 0, 0, 0);                                  \
    }                                                                              \
  } while (0)

  STAGE(0, 0);
  asm volatile("s_waitcnt vmcnt(0)" ::: "memory");
  __syncthreads();

  for (int l0 = 0; l0 < S_LEN; l0 += 128) {
    const int cur = (l0 >> 7) & 1;
    if (l0 + 128 < S_LEN) {
      STAGE(cur ^ 1, l0 + 128);                         // 4 loads stay in flight
      asm volatile("s_waitcnt vmcnt(4)" ::: "memory");  // own tile-t loads retired
    } else {
      asm volatile("s_waitcnt vmcnt(0)" ::: "memory");
    }
    asm volatile("s_barrier" ::: "memory");   // fenced barrier: all waves' t-loads landed
    COMPUTE32(cur, 0);
    COMPUTE32(cur, 1);
    asm volatile("s_barrier" ::: "memory");   // fenced: all reads done before overwrite
  }
#undef STAGE
#undef COMPUTE32

  // per-wave denom (64 keys/period share) per q: reduce over g
  #pragma unroll
  for (int qt = 0; qt < 2; ++qt) {
    lsum[qt] += __shfl_xor(lsum[qt], 16);
    lsum[qt] += __shfl_xor(lsum[qt], 32);
  }

  // ---- cross-kw reduction: kw=1 dumps O partials + lsum; kw=0 adds and writes ----
  float* red = reinterpret_cast<float*>(&KT[0][0][0]);   // 32KB scratch (KT dead now)
  if (kw == 1) {
    #pragma unroll
    for (int qt = 0; qt < 2; ++qt)
      #pragma unroll
      for (int dt = 0; dt < 4; ++dt)
        *reinterpret_cast<f32x4*>(red + (((qw * 2 + qt) * 4 + dt) << 8) + lane * 4) = oacc[qt][dt];
    if (lane < 16) { lsL[qw][0][lane] = lsum[0]; lsL[qw][1][lane] = lsum[1]; }
  }
  __syncthreads();
  if (kw == 0) {
    #pragma unroll
    for (int qt = 0; qt < 2; ++qt) {
      #pragma unroll
      for (int dt = 0; dt < 4; ++dt)
        oacc[qt][dt] += *reinterpret_cast<const f32x4*>(
            red + (((qw * 2 + qt) * 4 + dt) << 8) + lane * 4);
      const float rl = 1.f / (lsum[qt] + lsL[qw][qt][c]);
      unsigned short* ab = Ab + ((size_t)(n * S_LEN + qbase + qt * 16 + c)) * DM + h * DK;
      #pragma unroll
      for (int dt = 0; dt < 4; ++dt) {
        uint2 w;
        w.x = pkbf(oacc[qt][dt][0] * rl, oacc[qt][dt][1] * rl);
        w.y = pkbf(oacc[qt][dt][2] * rl, oacc[qt][dt][3] * rl);
        *reinterpret_cast<uint2*>(ab + dt * 16 + g * 4) = w;
      }
    }
  }
}

// ---------------- bf16 MFMA output projection: out = A @ W^T + b ----------------
__global__ __launch_bounds__(256, 2) void proj_kernel(const unsigned short* __restrict__ Ab,
                                                      const unsigned short* __restrict__ Wb,
                                                      const float* __restrict__ bias,
                                                      float* __restrict__ out) {
  __shared__ __align__(16) unsigned short At[2][128 * 64];  // [m][k], 128B rows
  __shared__ __align__(16) unsigned short Wt[2][64 * 64];   // [o][k], 128B rows

  const int m0 = blockIdx.x * 128;
  const int o0 = blockIdx.y * 64;
  const int wave = threadIdx.x >> 6;
  const int lane = threadIdx.x & 63;
  const int lr = lane & 15;
  const int lg = lane >> 4;
  const int r7 = lr & 7;
  const int wm = (wave >> 1) * 64;
  const int wn = (wave & 1) * 32;

  const int srow = lane >> 3;
  const int csrc = (lane & 7) ^ srow;
  const unsigned short* asrc = Ab + ((size_t)(m0 + wave * 32 + srow)) * DM + csrc * 8;
  const unsigned short* wsrc = Wb + ((size_t)(o0 + wave * 16 + srow)) * DM + csrc * 8;

  float bv[2];
  #pragma unroll
  for (int nf = 0; nf < 2; ++nf) bv[nf] = bias[o0 + wn + nf * 16 + lr];

  f32x4 acc[4][2];
  #pragma unroll
  for (int mf = 0; mf < 4; ++mf)
    #pragma unroll
    for (int nf = 0; nf < 2; ++nf) acc[mf][nf] = (f32x4){0.f, 0.f, 0.f, 0.f};

#define PSTAGE(B_, KB_) do {                                                       \
    _Pragma("unroll")                                                              \
    for (int u = 0; u < 4; ++u)                                                    \
      gl2lds16(asrc + (size_t)(u * 8) * DM + (KB_), &At[B_][(wave * 32 + u * 8) * 64]); \
    _Pragma("unroll")                                                              \
    for (int u = 0; u < 2; ++u)                                                    \
      gl2lds16(wsrc + (size_t)(u * 8) * DM + (KB_), &Wt[B_][(wave * 16 + u * 8) * 64]); \
  } while (0)

#define PCOMPUTE(B_) do {                                                          \
    _Pragma("unroll")                                                              \
    for (int kc = 0; kc < 2; ++kc) {                                               \
      const int sw = ((kc * 4 + lg) ^ r7) << 3;                                    \
      short8 af[4], wf[2];                                                         \
      _Pragma("unroll")                                                            \
      for (int mf = 0; mf < 4; ++mf)                                               \
        af[mf] = *reinterpret_cast<const short8*>(&At[B_][(wm + mf * 16 + lr) * 64 + sw]); \
      _Pragma("unroll")                                                            \
      for (int nf = 0; nf < 2; ++nf)                                               \
        wf[nf] = *reinterpret_cast<const short8*>(&Wt[B_][(wn + nf * 16 + lr) * 64 + sw]); \
      _Pragma("unroll")                                                            \
      for (int mf = 0; mf < 4; ++mf)                                               \
        _Pragma("unroll")                                                          \
        for (int nf = 0; nf < 2; ++nf)                                             \
          acc[mf][nf] = __builtin_amdgcn_mfma_f32_16x16x32_bf16(af[mf], wf[nf], acc[mf][nf], 0, 0, 0); \
    }                                                                              \
  } while (0)

  PSTAGE(0, 0);
  asm volatile("s_waitcnt vmcnt(0)" ::: "memory");
  __syncthreads();

  for (int kb = 0; kb < DM; kb += 64) {
    const int cur = (kb >> 6) & 1;
    if (kb + 64 < DM) PSTAGE(cur ^ 1, kb + 64);
    PCOMPUTE(cur);
    __syncthreads();
  }
#undef PSTAGE
#undef PCOMPUTE

  #pragma unroll
  for (int mf = 0; mf < 4; ++mf) {
    #pragma unroll
    for (int j = 0; j < 4; ++j) {
      float* op = out + (size_t)(m0 + wm + mf * 16 + lg * 4 + j) * DM + o0 + wn + lr;
      #pragma unroll
      for (int nf = 0; nf < 2; ++nf)
        op[nf * 16] = acc[mf][nf][j] + bv[nf];
    }
  }
}

extern "C" void kernel_launch(void* const* d_in, const int* in_sizes, int n_in,
                              void* d_out, int out_size, void* d_ws, size_t ws_size,
                              hipStream_t stream) {
  const float* Q = (const float*)d_in[0];
  const float* K = (const float*)d_in[1];
  const float* V = (const float*)d_in[2];
  const float* W = (const float*)d_in[3];
  const float* b = (const float*)d_in[4];
  float* out = (float*)d_out;

  // ws layout: Kb(8MB) | Vt(8MB) | Ab bf16(8MB) | Wb bf16(0.5MB)
  char* ws = (char*)d_ws;
  unsigned short* Kb = (unsigned short*)(ws);
  unsigned short* Vt = (unsigned short*)(ws + 8388608);
  unsigned short* Ab = (unsigned short*)(ws + 16777216);
  unsigned short* Wb = (unsigned short*)(ws + 25165824);

  prep_kernel<<<5376, 256, 0, stream>>>(K, V, W, Kb, Vt, Wb);
  attn_kernel<<<dim3(16, 32), 512, 0, stream>>>(Q, Kb, Vt, Ab);
  proj_kernel<<<dim3(64, 8), 256, 0, stream>>>(Ab, Wb, b, out);
}

// Round 19
// 68.004 us; speedup vs baseline: 1.2757x; 1.0139x over previous
//
#include <hip/hip_runtime.h>
#include <hip/hip_bf16.h>
#include <cstdint>
#include <cstddef>

#define S_LEN 2048
#define DM 512
#define DK 64

typedef __attribute__((ext_vector_type(4))) float f32x4;
typedef __attribute__((ext_vector_type(8))) short short8;
typedef __attribute__((ext_vector_type(8))) _Float16 f16x8;

__device__ __forceinline__ unsigned short f2bf(float f) {
  union { float f; uint32_t u; } c; c.f = f;
  uint32_t u = c.u;
  u += 0x7FFF + ((u >> 16) & 1);   // round-to-nearest-even
  return (unsigned short)(u >> 16);
}

__device__ __forceinline__ unsigned short f2h(float f) {
  union { _Float16 h; unsigned short u; } c; c.h = (_Float16)f; return c.u;
}

__device__ __forceinline__ unsigned int pkbf(float a, float b) {
  union { __hip_bfloat162 h; unsigned int u; } c;
  c.h = __float22bfloat162_rn(make_float2(a, b));
  return c.u;
}

__device__ __forceinline__ unsigned int pkh(float a, float b) {
  auto pk = __builtin_amdgcn_cvt_pkrtz(a, b);   // __fp16 ext_vector(2)
  union { decltype(pk) h; unsigned int u; } c;
  c.h = pk;
  return c.u;
}

// load 8 fp32, scale, round to bf16x8 (packed)
__device__ __forceinline__ short8 ldq8(const float* p, float s) {
  float4 a = *reinterpret_cast<const float4*>(p);
  float4 b = *reinterpret_cast<const float4*>(p + 4);
  union { short8 v; unsigned int u[4]; } r;
  r.u[0] = pkbf(a.x * s, a.y * s);
  r.u[1] = pkbf(a.z * s, a.w * s);
  r.u[2] = pkbf(b.x * s, b.y * s);
  r.u[3] = pkbf(b.z * s, b.w * s);
  return r.v;
}

// async global -> LDS, 16B per lane, LDS dest = wave-uniform base + lane*16
__device__ __forceinline__ void gl2lds16(const unsigned short* g, unsigned short* l) {
  __builtin_amdgcn_global_load_lds(
      (const __attribute__((address_space(1))) unsigned int*)g,
      (__attribute__((address_space(3))) unsigned int*)l, 16, 0, 0);
}

// exchange: a.lanes[32:63] <-> b.lanes[0:31]
#define SWAP32(a, b) asm volatile("v_permlane32_swap_b32 %0, %1" : "+v"(a), "+v"(b))
// exchange within 32-lane halves: a.lanes[16:31]<->b.lanes[0:15], a[48:63]<->b[32:47]
#define SWAP16(a, b) asm volatile("v_permlane16_swap_b32 %0, %1" : "+v"(a), "+v"(b))

// ---------------- fused prep: K->bf16, W->bf16, V->f16 transposed ----------------
__global__ __launch_bounds__(256) void prep_kernel(const float* __restrict__ K,
                                                   const float* __restrict__ V,
                                                   const float* __restrict__ W,
                                                   unsigned short* __restrict__ Kb,
                                                   unsigned short* __restrict__ Vt,
                                                   unsigned short* __restrict__ Wb) {
  __shared__ unsigned short tile[64][66];
  const int bid = blockIdx.x;
  const int t = threadIdx.x;
  if (bid < 4096) {                      // K convert -> bf16
    int i = (bid * 256 + t) * 4;
    float4 v = *reinterpret_cast<const float4*>(K + i);
    ushort4 o;
    o.x = f2bf(v.x); o.y = f2bf(v.y); o.z = f2bf(v.z); o.w = f2bf(v.w);
    *reinterpret_cast<ushort4*>(Kb + i) = o;
  } else if (bid < 4352) {               // W convert -> bf16
    int i = ((bid - 4096) * 256 + t) * 4;
    float4 v = *reinterpret_cast<const float4*>(W + i);
    ushort4 o;
    o.x = f2bf(v.x); o.y = f2bf(v.y); o.z = f2bf(v.z); o.w = f2bf(v.w);
    *reinterpret_cast<ushort4*>(Wb + i) = o;
  } else {                               // V transpose -> f16: Vt[nh][d][l]
    const int r = bid - 4352;            // 1024 blocks
    const int lt = r & 31;
    const int nh = r >> 5;
    const int n = nh >> 3, h = nh & 7;
    #pragma unroll
    for (int it = 0; it < 16; ++it) {
      int e = it * 256 + t;
      int l = e >> 6, d = e & 63;
      float v = V[((size_t)(n * S_LEN + lt * 64 + l)) * DM + h * DK + d];
      tile[l][d] = f2h(v);
    }
    __syncthreads();
    #pragma unroll
    for (int it = 0; it < 16; ++it) {
      int e = it * 256 + t;
      int d = e >> 6, l = e & 63;
      Vt[((size_t)(nh * DK + d)) * S_LEN + lt * 64 + l] = tile[l][d];
    }
  }
}

// ---------------- flash attention: r18 + T5 s_setprio around MFMA clusters ----------------
// r16/r18 geometry: KBLK=128, 8 waves (4qw x 2kw), counted vmcnt(4) + fenced s_barrier
// (race-fixed, verified r18). NEW: setprio(1) around each COMPUTE32's MFMA-dense region --
// wave role-diversity here (K-stagers / V-stagers / kw-split) is the m191 regime where
// setprio paid +4-7% on attention.
__global__ __launch_bounds__(512, 4) void attn_kernel(const float* __restrict__ Qf,
                                                      const unsigned short* __restrict__ Kb,
                                                      const unsigned short* __restrict__ Vt,
                                                      unsigned short* __restrict__ Ab) {
  __shared__ __align__(16) unsigned short KT[2][2][64 * 64];  // [buf][sub][key][d] bf16
  __shared__ __align__(16) unsigned short VT[2][2][64 * 64];  // [buf][sub][d][key] f16
  __shared__ float lsL[4][2][16];                             // [qw][qt][c] kw=1 partials

  // T1: bijective remap so XCD x handles nh in [4x, 4x+4)
  const int dlin = blockIdx.x + 16 * blockIdx.y;   // grid (16,32), 512 blocks
  const int xcd = dlin & 7;
  const int mm = dlin >> 3;                        // 0..63
  const int nh = xcd * 4 + (mm & 3);
  const int qtb = mm >> 2;                         // 0..15
  const int n = nh >> 3, h = nh & 7;
  const int wave = threadIdx.x >> 6;               // 0..7
  const int lane = threadIdx.x & 63;
  const int c = lane & 15;          // MFMA row/col index
  const int g = lane >> 4;          // lane group 0..3
  const int qw = wave >> 1;         // q-quarter 0..3
  const int kw = wave & 1;          // key-subtile this wave consumes
  const int c7 = c & 7;

  const int qbase = qtb * 128 + qw * 32;
  const float C2 = 0.063758716f;    // log2(e)/sqrt(512), folded into Q

  // Q B-fragments (16x16x32): lane (c,g) holds Q[qbase+qt*16+c][dkc*32+g*8+e]
  short8 qfrag[2][2];
  #pragma unroll
  for (int qt = 0; qt < 2; ++qt)
    #pragma unroll
    for (int dkc = 0; dkc < 2; ++dkc)
      qfrag[qt][dkc] = ldq8(
          Qf + ((size_t)(n * S_LEN + qbase + qt * 16 + c)) * DM + h * DK + dkc * 32 + g * 8, C2);

  f32x4 oacc[2][4];
  #pragma unroll
  for (int qt = 0; qt < 2; ++qt)
    #pragma unroll
    for (int dt = 0; dt < 4; ++dt) oacc[qt][dt] = (f32x4){0.f, 0.f, 0.f, 0.f};
  float lsum[2] = {0.f, 0.f};

  // Staging: waves 0-3 stage K (sub=(w>>1)&1, half=w&1 -> 32 rows), waves 4-7 stage V.
  // 4 gl_lds units of 8 rows x 128B each. Pre-swizzled source chunk (rule #21).
  const int srow = lane >> 3;
  const int csrc = (lane & 7) ^ srow;
  const bool isK = (wave < 4);
  const int sub = (wave >> 1) & 1;
  const int half = wave & 1;
  const unsigned short* sbase = isK
      ? Kb + ((size_t)(n * S_LEN + sub * 64 + half * 32 + srow)) * DM + h * DK + csrc * 8
      : Vt + ((size_t)(nh * DK + half * 32 + srow)) * S_LEN + sub * 64 + csrc * 8;
  unsigned short* dbase[2] = {
      isK ? &KT[0][sub][(half * 32) * 64] : &VT[0][sub][(half * 32) * 64],
      isK ? &KT[1][sub][(half * 32) * 64] : &VT[1][sub][(half * 32) * 64] };

#define STAGE(B_, L0_) do {                                                        \
    if (isK) {                                                                     \
      _Pragma("unroll")                                                            \
      for (int u = 0; u < 4; ++u)                                                  \
        gl2lds16(sbase + (size_t)((L0_) + u * 8) * DM, dbase[B_] + (u * 8) * 64);  \
    } else {                                                                       \
      _Pragma("unroll")                                                            \
      for (int u = 0; u < 4; ++u)                                                  \
        gl2lds16(sbase + (size_t)(u * 8) * S_LEN + (L0_), dbase[B_] + (u * 8) * 64); \
    }                                                                              \
  } while (0)

  // one 32-key group (ks2) of this wave's sub-tile: r13/r15/r16's proven COMPUTE body
  // with T5 setprio around the MFMA-dense region.
#define COMPUTE32(B_, KS2_) do {                                                   \
    short8 kf[2][2];                                                               \
    _Pragma("unroll")                                                              \
    for (int ks = 0; ks < 2; ++ks)                                                 \
      _Pragma("unroll")                                                            \
      for (int dkc = 0; dkc < 2; ++dkc)                                            \
        kf[ks][dkc] = *reinterpret_cast<const short8*>(                            \
            &KT[B_][kw][((KS2_) * 32 + ks * 16 + c) * 64 + (((dkc * 4 + g) ^ c7) << 3)]); \
    f32x4 s[2][2];                                                                 \
    _Pragma("unroll")                                                              \
    for (int qt = 0; qt < 2; ++qt)                                                 \
      _Pragma("unroll")                                                            \
      for (int ks = 0; ks < 2; ++ks) s[qt][ks] = (f32x4){0.f, 0.f, 0.f, 0.f};      \
    __builtin_amdgcn_s_setprio(1);                                                 \
    _Pragma("unroll")                                                              \
    for (int dkc = 0; dkc < 2; ++dkc)                                              \
      _Pragma("unroll")                                                            \
      for (int ks = 0; ks < 2; ++ks)                                               \
        _Pragma("unroll")                                                          \
        for (int qt = 0; qt < 2; ++qt)                                             \
          s[qt][ks] = __builtin_amdgcn_mfma_f32_16x16x32_bf16(                     \
              kf[ks][dkc], qfrag[qt][dkc], s[qt][ks], 0, 0, 0);                    \
    __builtin_amdgcn_s_setprio(0);                                                 \
    union { f16x8 v; unsigned int u[4]; } pf[2];                                   \
    _Pragma("unroll")                                                              \
    for (int qt = 0; qt < 2; ++qt) {                                               \
      float pa0 = __builtin_amdgcn_exp2f(s[qt][0][0]);                             \
      float pa1 = __builtin_amdgcn_exp2f(s[qt][0][1]);                             \
      float pa2 = __builtin_amdgcn_exp2f(s[qt][0][2]);                             \
      float pa3 = __builtin_amdgcn_exp2f(s[qt][0][3]);                             \
      float pb0 = __builtin_amdgcn_exp2f(s[qt][1][0]);                             \
      float pb1 = __builtin_amdgcn_exp2f(s[qt][1][1]);                             \
      float pb2 = __builtin_amdgcn_exp2f(s[qt][1][2]);                             \
      float pb3 = __builtin_amdgcn_exp2f(s[qt][1][3]);                             \
      lsum[qt] += ((pa0 + pa1) + (pa2 + pa3)) + ((pb0 + pb1) + (pb2 + pb3));       \
      unsigned int pA = pkh(pa0, pa1);                                             \
      unsigned int pB = pkh(pa2, pa3);                                             \
      unsigned int pC = pkh(pb0, pb1);                                             \
      unsigned int pD = pkh(pb2, pb3);                                             \
      SWAP32(pA, pC); SWAP32(pB, pD);                                              \
      SWAP16(pA, pC); SWAP16(pB, pD);                                              \
      pf[qt].u[0] = pA; pf[qt].u[1] = pB; pf[qt].u[2] = pC; pf[qt].u[3] = pD;      \
    }                                                                              \
    __builtin_amdgcn_s_setprio(1);                                                 \
    _Pragma("unroll")                                                              \
    for (int dt = 0; dt < 4; ++dt) {                                               \
      const f16x8 vf = *reinterpret_cast<const f16x8*>(                            \
          &VT[B_][kw][(dt * 16 + c) * 64 + ((((KS2_) * 4 + g) ^ c7) << 3)]);       \
      _Pragma("unroll")                                                            \
      for (int qt = 0; qt < 2; ++qt)                                               \
        oacc[qt][dt] = __builtin_amdgcn_mfma_f32_16x16x32_f16(                     \
            vf, pf[qt].v, oacc[qt][dt], 0, 0, 0);                                  \
    }                                                                              \
    __builtin_amdgcn_s_setprio(0);                                                 \
  } while (0)

  STAGE(0, 0);
  asm volatile("s_waitcnt vmcnt(0)" ::: "memory");
  __syncthreads();

  for (int l0 = 0; l0 < S_LEN; l0 += 128) {
    const int cur = (l0 >> 7) & 1;
    if (l0 + 128 < S_LEN) {
      STAGE(cur ^ 1, l0 + 128);                         // 4 loads stay in flight
      asm volatile("s_waitcnt vmcnt(4)" ::: "memory");  // own tile-t loads retired
    } else {
      asm volatile("s_waitcnt vmcnt(0)" ::: "memory");
    }
    asm volatile("s_barrier" ::: "memory");   // fenced barrier: all waves' t-loads landed
    COMPUTE32(cur, 0);
    COMPUTE32(cur, 1);
    asm volatile("s_barrier" ::: "memory");   // fenced: all reads done before overwrite
  }
#undef STAGE
#undef COMPUTE32

  // per-wave denom (64 keys/period share) per q: reduce over g
  #pragma unroll
  for (int qt = 0; qt < 2; ++qt) {
    lsum[qt] += __shfl_xor(lsum[qt], 16);
    lsum[qt] += __shfl_xor(lsum[qt], 32);
  }

  // ---- cross-kw reduction: kw=1 dumps O partials + lsum; kw=0 adds and writes ----
  float* red = reinterpret_cast<float*>(&KT[0][0][0]);   // 32KB scratch (KT dead now)
  if (kw == 1) {
    #pragma unroll
    for (int qt = 0; qt < 2; ++qt)
      #pragma unroll
      for (int dt = 0; dt < 4; ++dt)
        *reinterpret_cast<f32x4*>(red + (((qw * 2 + qt) * 4 + dt) << 8) + lane * 4) = oacc[qt][dt];
    if (lane < 16) { lsL[qw][0][lane] = lsum[0]; lsL[qw][1][lane] = lsum[1]; }
  }
  __syncthreads();
  if (kw == 0) {
    #pragma unroll
    for (int qt = 0; qt < 2; ++qt) {
      #pragma unroll
      for (int dt = 0; dt < 4; ++dt)
        oacc[qt][dt] += *reinterpret_cast<const f32x4*>(
            red + (((qw * 2 + qt) * 4 + dt) << 8) + lane * 4);
      const float rl = 1.f / (lsum[qt] + lsL[qw][qt][c]);
      unsigned short* ab = Ab + ((size_t)(n * S_LEN + qbase + qt * 16 + c)) * DM + h * DK;
      #pragma unroll
      for (int dt = 0; dt < 4; ++dt) {
        uint2 w;
        w.x = pkbf(oacc[qt][dt][0] * rl, oacc[qt][dt][1] * rl);
        w.y = pkbf(oacc[qt][dt][2] * rl, oacc[qt][dt][3] * rl);
        *reinterpret_cast<uint2*>(ab + dt * 16 + g * 4) = w;
      }
    }
  }
}

// ---------------- bf16 MFMA output projection: out = A @ W^T + b ----------------
__global__ __launch_bounds__(256, 2) void proj_kernel(const unsigned short* __restrict__ Ab,
                                                      const unsigned short* __restrict__ Wb,
                                                      const float* __restrict__ bias,
                                                      float* __restrict__ out) {
  __shared__ __align__(16) unsigned short At[2][128 * 64];  // [m][k], 128B rows
  __shared__ __align__(16) unsigned short Wt[2][64 * 64];   // [o][k], 128B rows

  const int m0 = blockIdx.x * 128;
  const int o0 = blockIdx.y * 64;
  const int wave = threadIdx.x >> 6;
  const int lane = threadIdx.x & 63;
  const int lr = lane & 15;
  const int lg = lane >> 4;
  const int r7 = lr & 7;
  const int wm = (wave >> 1) * 64;
  const int wn = (wave & 1) * 32;

  const int srow = lane >> 3;
  const int csrc = (lane & 7) ^ srow;
  const unsigned short* asrc = Ab + ((size_t)(m0 + wave * 32 + srow)) * DM + csrc * 8;
  const unsigned short* wsrc = Wb + ((size_t)(o0 + wave * 16 + srow)) * DM + csrc * 8;

  float bv[2];
  #pragma unroll
  for (int nf = 0; nf < 2; ++nf) bv[nf] = bias[o0 + wn + nf * 16 + lr];

  f32x4 acc[4][2];
  #pragma unroll
  for (int mf = 0; mf < 4; ++mf)
    #pragma unroll
    for (int nf = 0; nf < 2; ++nf) acc[mf][nf] = (f32x4){0.f, 0.f, 0.f, 0.f};

#define PSTAGE(B_, KB_) do {                                                       \
    _Pragma("unroll")                                                              \
    for (int u = 0; u < 4; ++u)                                                    \
      gl2lds16(asrc + (size_t)(u * 8) * DM + (KB_), &At[B_][(wave * 32 + u * 8) * 64]); \
    _Pragma("unroll")                                                              \
    for (int u = 0; u < 2; ++u)                                                    \
      gl2lds16(wsrc + (size_t)(u * 8) * DM + (KB_), &Wt[B_][(wave * 16 + u * 8) * 64]); \
  } while (0)

#define PCOMPUTE(B_) do {                                                          \
    _Pragma("unroll")                                                              \
    for (int kc = 0; kc < 2; ++kc) {                                               \
      const int sw = ((kc * 4 + lg) ^ r7) << 3;                                    \
      short8 af[4], wf[2];                                                         \
      _Pragma("unroll")                                                            \
      for (int mf = 0; mf < 4; ++mf)                                               \
        af[mf] = *reinterpret_cast<const short8*>(&At[B_][(wm + mf * 16 + lr) * 64 + sw]); \
      _Pragma("unroll")                                                            \
      for (int nf = 0; nf < 2; ++nf)                                               \
        wf[nf] = *reinterpret_cast<const short8*>(&Wt[B_][(wn + nf * 16 + lr) * 64 + sw]); \
      _Pragma("unroll")                                                            \
      for (int mf = 0; mf < 4; ++mf)                                               \
        _Pragma("unroll")                                                          \
        for (int nf = 0; nf < 2; ++nf)                                             \
          acc[mf][nf] = __builtin_amdgcn_mfma_f32_16x16x32_bf16(af[mf], wf[nf], acc[mf][nf], 0, 0, 0); \
    }                                                                              \
  } while (0)

  PSTAGE(0, 0);
  asm volatile("s_waitcnt vmcnt(0)" ::: "memory");
  __syncthreads();

  for (int kb = 0; kb < DM; kb += 64) {
    const int cur = (kb >> 6) & 1;
    if (kb + 64 < DM) PSTAGE(cur ^ 1, kb + 64);
    PCOMPUTE(cur);
    __syncthreads();
  }
#undef PSTAGE
#undef PCOMPUTE

  #pragma unroll
  for (int mf = 0; mf < 4; ++mf) {
    #pragma unroll
    for (int j = 0; j < 4; ++j) {
      float* op = out + (size_t)(m0 + wm + mf * 16 + lg * 4 + j) * DM + o0 + wn + lr;
      #pragma unroll
      for (int nf = 0; nf < 2; ++nf)
        op[nf * 16] = acc[mf][nf][j] + bv[nf];
    }
  }
}

extern "C" void kernel_launch(void* const* d_in, const int* in_sizes, int n_in,
                              void* d_out, int out_size, void* d_ws, size_t ws_size,
                              hipStream_t stream) {
  const float* Q = (const float*)d_in[0];
  const float* K = (const float*)d_in[1];
  const float* V = (const float*)d_in[2];
  const float* W = (const float*)d_in[3];
  const float* b = (const float*)d_in[4];
  float* out = (float*)d_out;

  // ws layout: Kb(8MB) | Vt(8MB) | Ab bf16(8MB) | Wb bf16(0.5MB)
  char* ws = (char*)d_ws;
  unsigned short* Kb = (unsigned short*)(ws);
  unsigned short* Vt = (unsigned short*)(ws + 8388608);
  unsigned short* Ab = (unsigned short*)(ws + 16777216);
  unsigned short* Wb = (unsigned short*)(ws + 25165824);

  prep_kernel<<<5376, 256, 0, stream>>>(K, V, W, Kb, Vt, Wb);
  attn_kernel<<<dim3(16, 32), 512, 0, stream>>>(Q, Kb, Vt, Ab);
  proj_kernel<<<dim3(64, 8), 256, 0, stream>>>(Ab, Wb, b, out);
}